// Round 17
// baseline (55.127 us; speedup 1.0000x reference)
//
#include <hip/hip_runtime.h>
#include <hip/hip_bf16.h>
#include <math.h>

// SimCLR NT-Xent: B=4096, D=256, n=8192, T=0.5.
// z' = sqrt(K1) * rownorm(concat(a,b)) as bf16, row-swizzled in global:
//   stored_byte_in_row = logical_byte ^ ((row&7)<<4)
// MFMA(z', z'^T) = K1 * dot -> exp(sim) = exp2(MFMA out).  E SYMMETRIC.
// Round 17: 8-phase-template port (T3+T4 structure, not a graft):
//  - 256x128 tiles, 4 waves (2M x 2N), per-wave C = 128x64 REGISTER-RESIDENT
//    (acc[8][4] f32x4 = 128 VGPR). A and B both LDS-staged in fragment order
//    (R13 zero-conflict layout), BK=32, 8 K-steps x 2 phases.
//  - Each phase: {ds_read frags || stage 3 slots(K-step+1) -> lgkmcnt(0) ->
//    sbar -> setprio(1) 16 MFMA setprio(0) -> sbar}; vmcnt(0) only at K-step
//    end. NO per-phase exp flush: all exp2 in a once-per-block epilogue.
//  - Triangular circulant cover at 256x128: 1088 equal blocks (t, g=0..16,
//    h=0..1), u=(t+g)&31, cols u*256+h*128. Row-sums -> slot 2g+h (0..33);
//    col-sums (g=1..15) -> slot 33+g (34..48). Every slot written once;
//    distances 0/1-16 row-side, 17-31 col-side: complete cover, 3% redundant.
// loss = mean( ln2 * (log2(S_i - exp2(self_i)) - K1*posdot_i) ).

#define NROWS 8192
#define BHALF 4096
#define DDIM  256
#define ROWB  512
#define NKS   8                   // K-steps (K=256, BK=32)
#define BUFB  (24 * 1024)         // 24 slots x 1KB (A 16 + B 8)
#define SSTRIDE 64
#define NSLOT 49

#define SQRT_K1 1.6986436f        // sqrt(2*log2(e))
#define LN2F 0.6931471805599453f

typedef __attribute__((ext_vector_type(8))) __bf16 bf16x8;
typedef __attribute__((ext_vector_type(4))) float f32x4;

#if __has_builtin(__builtin_amdgcn_exp2f)
#define FEXP2(x) __builtin_amdgcn_exp2f(x)
#else
#define FEXP2(x) __exp2f(x)
#endif
#if __has_builtin(__builtin_amdgcn_logf)
#define FLOG2(x) __builtin_amdgcn_logf(x)
#else
#define FLOG2(x) __log2f(x)
#endif

__device__ __forceinline__ float bfu(unsigned short u) {
  union { unsigned v; float f; } x; x.v = ((unsigned)u) << 16; return x.f;
}

// ---------------- Kernel 1: normalize+scale rows -> swizzled bf16 ----------
__global__ __launch_bounds__(256) void norm_kernel(
    const float* __restrict__ a, const float* __restrict__ b,
    char* __restrict__ zb, float* __restrict__ selfdot) {
  int row = blockIdx.x * 4 + (threadIdx.x >> 6);
  int lane = threadIdx.x & 63;
  const float* src = (row < BHALF) ? (a + (size_t)row * DDIM)
                                   : (b + (size_t)(row - BHALF) * DDIM);
  float4 v = ((const float4*)src)[lane];
  float ss = v.x * v.x + v.y * v.y + v.z * v.z + v.w * v.w;
  #pragma unroll
  for (int m = 1; m < 64; m <<= 1) ss += __shfl_xor(ss, m, 64);
  float inv = rsqrtf(ss);
  inv = inv * (1.5f - 0.5f * ss * inv * inv);
  float sc = inv * SQRT_K1;

  union { __hip_bfloat16 h; unsigned short u; } c0, c1, c2, c3;
  c0.h = __float2bfloat16(v.x * sc);
  c1.h = __float2bfloat16(v.y * sc);
  c2.h = __float2bfloat16(v.z * sc);
  c3.h = __float2bfloat16(v.w * sc);
  float q0 = bfu(c0.u), q1 = bfu(c1.u), q2 = bfu(c2.u), q3 = bfu(c3.u);
  float sq = q0 * q0 + q1 * q1 + q2 * q2 + q3 * q3;
  #pragma unroll
  for (int m = 1; m < 64; m <<= 1) sq += __shfl_xor(sq, m, 64);

  ushort4 o = make_ushort4(c0.u, c1.u, c2.u, c3.u);
  int off = row * ROWB + ((lane * 8) ^ ((row & 7) << 4));
  *(ushort4*)(zb + off) = o;
  if (lane == 0) selfdot[row] = sq;
}

// ---------------- Kernel 2: triangular z z^T, 8-phase template -------------
// 1088 blocks x 256 thr. Block (t,g,h): rows t*256, cols (t+g)%32*256+h*128.
__global__ __launch_bounds__(256, 2) void sim_kernel(
    const char* __restrict__ zb, float* __restrict__ s_part) {
  __shared__ __align__(16) char lds[2 * BUFB];   // 48 KiB double buffer
  __shared__ float cred_row[2][256];             // [wn][row]  2 KiB
  __shared__ float cred_col[2][128];             // [wm][col]  1 KiB

  int bid = blockIdx.x;
  int h = bid & 1;
  int tg = bid >> 1;
  int t = tg & 31;
  int g = tg >> 5;                 // 0..16
  int u = (t + g) & 31;
  int r0 = t * 256;                // block row base
  int c0 = u * 256 + h * 128;      // block col base

  int wave = threadIdx.x >> 6;     // 0..3
  int wm = wave >> 1, wn = wave & 1;
  int lane = threadIdx.x & 63;
  int lrow = lane & 15;
  int kgrp = lane >> 4;
  int sw = (lrow & 7) << 4;

  f32x4 acc[8][4];
  #pragma unroll
  for (int mi = 0; mi < 8; ++mi)
    #pragma unroll
    for (int nj = 0; nj < 4; ++nj)
      acc[mi][nj] = (f32x4){0.f, 0.f, 0.f, 0.f};
  bf16x8 bfv[4];

  // stage slot s (0..15: A mi=s; 16..23: B nj=s-16) of K-step ks
  #define STAGE_SLOT(dstbuf, ks, s) do {                                      \
    int rowb_ = ((s) < 16) ? (r0 + (s) * 16) : (c0 + ((s) - 16) * 16);        \
    const char* g_ = zb + (size_t)(rowb_ + lrow) * ROWB +                     \
                     (((ks) * 64 + kgrp * 16) ^ sw);                          \
    char* l_ = lds + (dstbuf) * BUFB + (s) * 1024;                            \
    __builtin_amdgcn_global_load_lds(                                         \
        (const __attribute__((address_space(1))) void*)g_,                    \
        (__attribute__((address_space(3))) void*)l_, 16, 0, 0);               \
  } while (0)

  // one phase (P = 0/1): reads, stage, lgkm-fence, sbar, MFMA cluster, sbar
  #define PHASE(P) do {                                                       \
    const char* lb_ = lds + buf * BUFB + lane * 16;                           \
    bf16x8 afv[4];                                                            \
    _Pragma("unroll")                                                         \
    for (int i = 0; i < 4; ++i)                                               \
      afv[i] = *(const bf16x8*)(lb_ + (wm * 8 + (P) * 4 + i) * 1024);         \
    if ((P) == 0) {                                                           \
      _Pragma("unroll")                                                       \
      for (int nj = 0; nj < 4; ++nj)                                          \
        bfv[nj] = *(const bf16x8*)(lb_ + (16 + wn * 4 + nj) * 1024);          \
    }                                                                         \
    if (ks + 1 < NKS) {                                                       \
      STAGE_SLOT(buf ^ 1, ks + 1, wave + 4 * (3 * (P) + 0));                  \
      STAGE_SLOT(buf ^ 1, ks + 1, wave + 4 * (3 * (P) + 1));                  \
      STAGE_SLOT(buf ^ 1, ks + 1, wave + 4 * (3 * (P) + 2));                  \
    }                                                                         \
    asm volatile("s_waitcnt lgkmcnt(0)" ::: "memory");                        \
    __builtin_amdgcn_sched_barrier(0);                                        \
    __builtin_amdgcn_s_barrier();                                             \
    __builtin_amdgcn_s_setprio(1);                                            \
    _Pragma("unroll")                                                         \
    for (int i = 0; i < 4; ++i)                                               \
      _Pragma("unroll")                                                       \
      for (int nj = 0; nj < 4; ++nj)                                          \
        acc[(P) * 4 + i][nj] = __builtin_amdgcn_mfma_f32_16x16x32_bf16(       \
            afv[i], bfv[nj], acc[(P) * 4 + i][nj], 0, 0, 0);                  \
    __builtin_amdgcn_s_setprio(0);                                            \
    if ((P) == 1 && ks + 1 < NKS)                                             \
      asm volatile("s_waitcnt vmcnt(0)" ::: "memory");                        \
    __builtin_amdgcn_sched_barrier(0);                                        \
    __builtin_amdgcn_s_barrier();                                             \
  } while (0)

  // prologue: stage K-step 0 (6 slots per wave), drain, barrier
  #pragma unroll
  for (int i = 0; i < 6; ++i) STAGE_SLOT(0, 0, wave + 4 * i);
  asm volatile("s_waitcnt vmcnt(0)" ::: "memory");
  __builtin_amdgcn_sched_barrier(0);
  __builtin_amdgcn_s_barrier();

  for (int ks = 0; ks < NKS; ++ks) {
    int buf = ks & 1;
    PHASE(0);
    PHASE(1);
  }
  #undef PHASE
  #undef STAGE_SLOT

  // ---- epilogue: exp2 everything once; row + col partials ----
  float colp[4] = {0.f, 0.f, 0.f, 0.f};
  #pragma unroll
  for (int mi = 0; mi < 8; ++mi) {
    #pragma unroll
    for (int r = 0; r < 4; ++r) {
      float e0 = FEXP2(acc[mi][0][r]);
      float e1 = FEXP2(acc[mi][1][r]);
      float e2 = FEXP2(acc[mi][2][r]);
      float e3 = FEXP2(acc[mi][3][r]);
      colp[0] += e0; colp[1] += e1; colp[2] += e2; colp[3] += e3;
      float rs = (e0 + e1) + (e2 + e3);
      rs += __shfl_xor(rs, 1, 64);
      rs += __shfl_xor(rs, 2, 64);
      rs += __shfl_xor(rs, 4, 64);
      rs += __shfl_xor(rs, 8, 64);
      if (lrow == 0)
        cred_row[wn][wm * 128 + mi * 16 + kgrp * 4 + r] = rs;
    }
  }
  #pragma unroll
  for (int nj = 0; nj < 4; ++nj) {
    float v = colp[nj];
    v += __shfl_xor(v, 16, 64);
    v += __shfl_xor(v, 32, 64);
    if (kgrp == 0) cred_col[wm][wn * 64 + nj * 16 + lrow] = v;
  }
  __syncthreads();

  // combine + write: row slot 2g+h; col slot 33+g (g=1..15)
  {
    int i0 = threadIdx.x;
    float v = cred_row[0][i0] + cred_row[1][i0];
    s_part[(size_t)(r0 + i0) * SSTRIDE + (2 * g + h)] = v;
    if (g >= 1 && g <= 15 && i0 < 128) {
      float c = cred_col[0][i0] + cred_col[1][i0];
      s_part[(size_t)(c0 + i0) * SSTRIDE + (33 + g)] = c;
    }
  }
}

// ---------------- Kernel 3: per-row term (pos dot + assemble) --------------
__global__ __launch_bounds__(256) void rowterm_kernel(
    const char* __restrict__ zb, const float* __restrict__ s_part,
    const float* __restrict__ selfdot, float* __restrict__ bpart) {
  int wave = threadIdx.x >> 6;
  int lane = threadIdx.x & 63;
  int rbase = blockIdx.x * 16 + wave * 4;
  float wacc = 0.f;
  #pragma unroll
  for (int rr = 0; rr < 4; ++rr) {
    int i = rbase + rr;
    int j = i ^ BHALF;                       // (i+B) mod 2B
    int wo = (lane * 8) ^ ((i & 7) << 4);    // j&7 == i&7
    ushort4 zi = *(const ushort4*)(zb + (size_t)i * ROWB + wo);
    ushort4 zj = *(const ushort4*)(zb + (size_t)j * ROWB + wo);
    float dot = bfu(zi.x) * bfu(zj.x) + bfu(zi.y) * bfu(zj.y) +
                bfu(zi.z) * bfu(zj.z) + bfu(zi.w) * bfu(zj.w);
    float sp = (lane < NSLOT) ? s_part[(size_t)i * SSTRIDE + lane] : 0.f;
    #pragma unroll
    for (int m = 1; m < 64; m <<= 1) {
      dot += __shfl_xor(dot, m, 64);
      sp += __shfl_xor(sp, m, 64);
    }
    float S = sp - FEXP2(selfdot[i]);          // remove diagonal
    wacc += LN2F * (FLOG2(S) - dot);           // denom - pos
  }
  __shared__ float red[4];
  if (lane == 0) red[wave] = wacc;
  __syncthreads();
  if (threadIdx.x == 0)
    bpart[blockIdx.x] = red[0] + red[1] + red[2] + red[3];
}

// ---------------- Kernel 4: final sum --------------------------------------
__global__ __launch_bounds__(512) void final_kernel(
    const float* __restrict__ bpart, float* __restrict__ out) {
  int t = threadIdx.x;
  float v = bpart[t];
  #pragma unroll
  for (int m = 1; m < 64; m <<= 1) v += __shfl_xor(v, m, 64);
  __shared__ float r2[8];
  if ((t & 63) == 0) r2[t >> 6] = v;
  __syncthreads();
  if (t == 0) {
    float s = 0.f;
    #pragma unroll
    for (int w = 0; w < 8; ++w) s += r2[w];
    out[0] = s / (float)NROWS;
  }
}

// ---------------- Launcher --------------------------------------------------
extern "C" void kernel_launch(void* const* d_in, const int* in_sizes, int n_in,
                              void* d_out, int out_size, void* d_ws, size_t ws_size,
                              hipStream_t stream) {
  const float* a = (const float*)d_in[0];
  const float* b = (const float*)d_in[1];
  float* out = (float*)d_out;
  char* ws = (char*)d_ws;

  char* zb = ws;                                            // 4 MiB
  float* selfdot = (float*)(ws + (size_t)NROWS * ROWB);     // 32 KiB
  float* s_part = selfdot + NROWS;                          // 2 MiB [8192][64]
  float* bpart = s_part + (size_t)NROWS * SSTRIDE;          // 2 KiB

  hipLaunchKernelGGL(norm_kernel, dim3(NROWS / 4), dim3(256), 0, stream,
                     a, b, zb, selfdot);
  hipLaunchKernelGGL(sim_kernel, dim3(1088), dim3(256), 0, stream,
                     zb, s_part);
  hipLaunchKernelGGL(rowterm_kernel, dim3(512), dim3(256), 0, stream,
                     zb, s_part, selfdot, bpart);
  hipLaunchKernelGGL(final_kernel, dim3(1), dim3(512), 0, stream, bpart, out);
}